// Round 16
// baseline (96.747 us; speedup 1.0000x reference)
//
#include <hip/hip_runtime.h>
#include <stdint.h>

#define IN_F   4096
#define OUT_F  11008
#define BATCH  8
#define WAVES  4
#define RPW    8                  // rows per wave
#define RPB    (WAVES*RPW)        // 32 rows per block
#define NS     4                  // split-K slices
#define SLICE  (IN_F/NS)          // 1024 i per block
#define CHUNK  64                 // i-values per chunk
#define NCHUNK (SLICE/CHUNK)      // 16
#define SLOTI  (2*RPB*CHUNK + BATCH*CHUNK)  // 4608 ints = 18 KB/slot

typedef __attribute__((address_space(1))) const uint32_t* gas_t;
typedef __attribute__((address_space(3))) uint32_t* las_t;

// async global->LDS DMA, 16 B/lane (1 KB/instr): no VGPR destination
#define DMA16(gsrc, ldst) \
    __builtin_amdgcn_global_load_lds((gas_t)(gsrc), (las_t)(ldst), 16, 0, 0)

__device__ __forceinline__ float qins_decode(int code, int sgn, float d0, float d1) {
    // |w| = exp2(d0 + code*d1); sign bit straight from the int32 sign (+1 / -1)
    const float e = __builtin_amdgcn_exp2f(fmaf((float)code, d1, d0));
    const uint32_t m = ((uint32_t)sgn) & 0x80000000u;
    return __uint_as_float(__float_as_uint(e) ^ m);
}

// out[b][o] = bias[o]  (out not re-poisoned between replays; re-init each call)
__global__ void qins_init(const float* __restrict__ bias, float* __restrict__ out)
{
    const int o = blockIdx.x * 256 + threadIdx.x;
    const float bv = bias[o];
#pragma unroll
    for (int b = 0; b < BATCH; ++b)
        out[(size_t)b * OUT_F + o] = bv;
}

__global__ __launch_bounds__(256, 4)
void qins_main(const float* __restrict__ x,
               const uint32_t* __restrict__ stored,
               const uint32_t* __restrict__ sign,
               const float* __restrict__ log_min,
               const float* __restrict__ log_max,
               float* __restrict__ out)
{
    // slot (ints): [0,2048) stored 32x64 | [2048,4096) sign | [4096,4608) x 8x64
    __shared__ int lds[2][SLOTI];

    const int tid  = threadIdx.x;
    const int lane = tid & 63;
    const int wave = tid >> 6;
    const int rg   = blockIdx.x % (OUT_F / RPB);   // row group (consecutive
    const int s    = blockIdx.x / (OUT_F / RPB);   //   blocks share x slice)
    const int o0   = rg * RPB;
    const int i0   = s * SLICE;

    const float lmin = log_min[0];
    const float lmax = log_max[0];
    const float L2E  = 1.44269504088896340736f;
    // log2(|w|) = d0 + code*d1
    const float d1 = -(lmax - lmin) * (L2E / 254.0f);
    const float d0 = (lmin + (lmax - lmin) * (255.0f / 254.0f)) * L2E;

    // DMA sources: each DMA16 covers 4 rows (lane>>4 picks row, lane&15 the 16B)
    const int rsub = lane >> 4;
    const int csub = (lane & 15) * 4;
    const uint32_t* gsA = stored + (size_t)(o0 + 8 * wave + rsub) * IN_F + i0 + csub;
    const uint32_t* gsB = gsA + 4 * IN_F;
    const uint32_t* ggA = sign   + (size_t)(o0 + 8 * wave + rsub) * IN_F + i0 + csub;
    const uint32_t* ggB = ggA + 4 * IN_F;
    // x: wave 0 stages batches 0-3, wave 1 stages 4-7 (waves 2,3: pointer unused)
    const uint32_t* gxw = (const uint32_t*)x
                        + (size_t)((wave & 1) * 4 + rsub) * IN_F + i0 + csub;

#define ISSUE(T, K)                                                          \
    do {                                                                     \
        const int _ip = (K) * CHUNK;                                         \
        DMA16(gsA + _ip, &lds[T][wave * 512]);                               \
        DMA16(gsB + _ip, &lds[T][wave * 512 + 256]);                         \
        DMA16(ggA + _ip, &lds[T][2048 + wave * 512]);                        \
        DMA16(ggB + _ip, &lds[T][2048 + wave * 512 + 256]);                  \
        if (wave < 2)                                                        \
            DMA16(gxw + _ip, &lds[T][4096 + wave * 256]);                    \
    } while (0)

    float acc[RPW][BATCH];
#pragma unroll
    for (int r = 0; r < RPW; ++r)
#pragma unroll
        for (int b = 0; b < BATCH; ++b) acc[r][b] = 0.0f;

    ISSUE(0, 0);                 // stage chunk 0
    __syncthreads();

#pragma unroll 1
    for (int k = 0; k < NCHUNK; ++k) {
        const int cur = k & 1;
        if (k + 1 < NCHUNK)
            ISSUE(cur ^ 1, k + 1);       // next chunk in flight during compute

        // compute chunk k: wave's 8 rows x 8 batches; lane covers one i
        {
            float w8[RPW];
#pragma unroll
            for (int r = 0; r < RPW; ++r) {
                const int c_ = lds[cur][wave * 512 + r * 64 + lane];
                const int g_ = lds[cur][2048 + wave * 512 + r * 64 + lane];
                w8[r] = qins_decode(c_, g_, d0, d1);
            }
#pragma unroll
            for (int b = 0; b < BATCH; ++b) {
                const float xv = __int_as_float(lds[cur][4096 + b * 64 + lane]);
#pragma unroll
                for (int r = 0; r < RPW; ++r)
                    acc[r][b] = fmaf(w8[r], xv, acc[r][b]);
            }
        }
        __syncthreads();   // drains next chunk's DMAs + releases both slots
    }

    // butterfly-reduce the 64 (row,batch) partials across the wave
#pragma unroll
    for (int r = 0; r < RPW; ++r)
#pragma unroll
        for (int b = 0; b < BATCH; ++b) {
            float v = acc[r][b];
#pragma unroll
            for (int sft = 32; sft >= 1; sft >>= 1)
                v += __shfl_xor(v, sft, 64);
            acc[r][b] = v;
        }

    if (lane == 0) {
#pragma unroll
        for (int r = 0; r < RPW; ++r) {
            const int row = o0 + 8 * wave + r;
#pragma unroll
            for (int b = 0; b < BATCH; ++b)
                atomicAdd(out + (size_t)b * OUT_F + row, acc[r][b]);
        }
    }
#undef ISSUE
}

extern "C" void kernel_launch(void* const* d_in, const int* in_sizes, int n_in,
                              void* d_out, int out_size, void* d_ws, size_t ws_size,
                              hipStream_t stream)
{
    const float*    x      = (const float*)d_in[0];
    const uint32_t* stored = (const uint32_t*)d_in[1];
    const uint32_t* sign   = (const uint32_t*)d_in[2];
    const float*    lmin   = (const float*)d_in[3];
    const float*    lmax   = (const float*)d_in[4];
    const float*    bias   = (const float*)d_in[5];
    float* out = (float*)d_out;

    qins_init<<<dim3(OUT_F / 256), dim3(256), 0, stream>>>(bias, out);
    qins_main<<<dim3((OUT_F / RPB) * NS), dim3(256), 0, stream>>>(
        x, stored, sign, lmin, lmax, out);
}

// Round 18
// 69.573 us; speedup vs baseline: 1.3906x; 1.3906x over previous
//
#include <hip/hip_runtime.h>
#include <stdint.h>

#define IN_F   4096
#define OUT_F  11008
#define BATCH  8
#define WAVES  4
#define RPW    2                  // rows per wave
#define RPB    (WAVES*RPW)        // 8 rows per block
#define CHUNK  128                // i-values per chunk
#define NCHUNK (IN_F/CHUNK)       // 32
#define NSLOT  3                  // ring slots (12 KB each -> 36 KB)
#define SLOTI  (3*RPB*CHUNK)      // 3072 ints per slot
#define SLOTB  (SLOTI*4)          // 12288 bytes per slot

typedef __attribute__((address_space(1))) const uint32_t* gas_t;
typedef __attribute__((address_space(3))) uint32_t* las_t;
typedef int i32x2 __attribute__((ext_vector_type(2)));

// async global->LDS DMA, 16 B/lane (1 KB/instr): no VGPR destination
#define DMA16(gsrc, ldst) \
    __builtin_amdgcn_global_load_lds((gas_t)(gsrc), (las_t)(ldst), 16, 0, 0)

#define SBAR() __builtin_amdgcn_sched_barrier(0)
#define VWAIT(N)                                                             \
    do {                                                                     \
        asm volatile("s_waitcnt vmcnt(" #N ")" ::: "memory");                \
        SBAR();                                                              \
    } while (0)

// compiler-opaque LDS read: base VGPR + constant byte offset. The compiler
// cannot tie this to the global_load_lds DMAs -> no auto vmcnt(0) drain.
#define DSREAD(dst, addr, OFF)                                               \
    asm volatile("ds_read_b64 %0, %1 offset:" #OFF : "=v"(dst) : "v"(addr))

__device__ __forceinline__ float qins_decode(int code, int sgn, float d0, float d1) {
    // |w| = exp2(d0 + code*d1); sign bit straight from the int32 sign (+1 / -1)
    const float e = __builtin_amdgcn_exp2f(fmaf((float)code, d1, d0));
    const uint32_t m = ((uint32_t)sgn) & 0x80000000u;
    return __uint_as_float(__float_as_uint(e) ^ m);
}

__global__ __launch_bounds__(256, 4)
void qins_linear_kernel(const float* __restrict__ x,
                        const uint32_t* __restrict__ stored,
                        const uint32_t* __restrict__ sign,
                        const float* __restrict__ log_min,
                        const float* __restrict__ log_max,
                        const float* __restrict__ bias,
                        float* __restrict__ out)
{
    // slot (ints): [0,1024) stored 8x128 | [1024,2048) sign | [2048,3072) x
    // weight regions: wave w's segment = rows {2w,2w+1} at wave*256
    // x region: batch b at 2048 + b*128 (wave-INDEPENDENT — R17's bug)
    __shared__ int lds[NSLOT][SLOTI];

    const int tid  = threadIdx.x;
    const int lane = tid & 63;
    const int wave = tid >> 6;
    const int o0   = blockIdx.x * RPB;

    const float lmin = log_min[0];
    const float lmax = log_max[0];
    const float L2E  = 1.44269504088896340736f;
    // log2(|w|) = d0 + code*d1
    const float d1 = -(lmax - lmin) * (L2E / 254.0f);
    const float d0 = (lmin + (lmax - lmin) * (255.0f / 254.0f)) * L2E;

    // DMA sources: lanes 0-31 cover row 2w (128 ints), lanes 32-63 row 2w+1
    const int sub = lane >> 5;
    const int i32 = (lane & 31) * 4;
    const uint32_t* gs = stored + (size_t)(o0 + 2 * wave + sub) * IN_F + i32;
    const uint32_t* gg = sign   + (size_t)(o0 + 2 * wave + sub) * IN_F + i32;
    const uint32_t* gx = (const uint32_t*)x + (size_t)(2 * wave + sub) * IN_F + i32;

#define ISSUE(T, K)                                                          \
    do {                                                                     \
        const int _ip = (K) * CHUNK;                                         \
        DMA16(gs + _ip, &lds[T][wave * 256]);                                \
        DMA16(gg + _ip, &lds[T][1024 + wave * 256]);                         \
        DMA16(gx + _ip, &lds[T][2048 + wave * 256]);                         \
    } while (0)

    float acc[RPW][BATCH];
#pragma unroll
    for (int r = 0; r < RPW; ++r)
#pragma unroll
        for (int b = 0; b < BATCH; ++b) acc[r][b] = 0.0f;

    // two per-lane LDS byte bases for slot 0:
    //   baseW: this wave's weight segment (stored at +0/+512, sign at +4096/+4608)
    //   baseX: x region start (batch b at immediate b*512)
    const uint32_t ldsb  = (uint32_t)(uintptr_t)(las_t)&lds[0][0];
    const uint32_t baseW = ldsb + (uint32_t)(wave * 256 + lane * 2) * 4u;
    const uint32_t baseX = ldsb + (uint32_t)(2048 + lane * 2) * 4u;

    // prologue: chunks 0 and 1 in flight (6 outstanding DMAs per wave)
    ISSUE(0, 0);
    ISSUE(1, 1);
    SBAR();

    int cur = 0, iss = 2;        // compute slot, issue slot (mod-3 counters)
#pragma unroll 1
    for (int k = 0; k < NCHUNK; ++k) {
        // retire exactly chunk k's 3 DMAs; chunk k+1's stay in flight
        if (k < NCHUNK - 1) VWAIT(3);
        else                VWAIT(0);
        __builtin_amdgcn_s_barrier();   // raw barrier: no vmcnt(0) drain
        SBAR();

        if (k + 2 < NCHUNK)
            ISSUE(iss, k + 2);          // refill reclaimed slot
        SBAR();

        // compute chunk k via compiler-opaque asm ds_reads
        {
            const uint32_t aw = baseW + (uint32_t)cur * SLOTB;
            const uint32_t ax = baseX + (uint32_t)cur * SLOTB;
            i32x2 c0, c1, g0, g1, xv[BATCH];
            DSREAD(c0, aw, 0);       // stored row 2w
            DSREAD(c1, aw, 512);     // stored row 2w+1
            DSREAD(g0, aw, 4096);    // sign row 2w
            DSREAD(g1, aw, 4608);    // sign row 2w+1
            DSREAD(xv[0], ax, 0);    // x batch 0
            DSREAD(xv[1], ax, 512);
            DSREAD(xv[2], ax, 1024);
            DSREAD(xv[3], ax, 1536);
            DSREAD(xv[4], ax, 2048);
            DSREAD(xv[5], ax, 2560);
            DSREAD(xv[6], ax, 3072);
            DSREAD(xv[7], ax, 3584);
            asm volatile("s_waitcnt lgkmcnt(0)" ::: "memory");
            SBAR();                  // rule #18: fence reg-only ops behind wait

            const float w00 = qins_decode(c0.x, g0.x, d0, d1);
            const float w01 = qins_decode(c0.y, g0.y, d0, d1);
            const float w10 = qins_decode(c1.x, g1.x, d0, d1);
            const float w11 = qins_decode(c1.y, g1.y, d0, d1);
#pragma unroll
            for (int b = 0; b < BATCH; ++b) {
                const float xlo = __int_as_float(xv[b].x);
                const float xhi = __int_as_float(xv[b].y);
                acc[0][b] = fmaf(w01, xhi, fmaf(w00, xlo, acc[0][b]));
                acc[1][b] = fmaf(w11, xhi, fmaf(w10, xlo, acc[1][b]));
            }
        }

        cur = (cur == NSLOT - 1) ? 0 : cur + 1;
        iss = (iss == NSLOT - 1) ? 0 : iss + 1;
    }

    // butterfly reduction of the 16 (row,batch) partials across the wave
#pragma unroll
    for (int r = 0; r < RPW; ++r)
#pragma unroll
        for (int b = 0; b < BATCH; ++b) {
            float v = acc[r][b];
#pragma unroll
            for (int s = 32; s >= 1; s >>= 1)
                v += __shfl_xor(v, s, 64);
            acc[r][b] = v;
        }

    if (lane == 0) {
#pragma unroll
        for (int r = 0; r < RPW; ++r) {
            const int row = o0 + 2 * wave + r;
            const float bv = bias[row];
#pragma unroll
            for (int b = 0; b < BATCH; ++b)
                out[(size_t)b * OUT_F + row] = acc[r][b] + bv;
        }
    }
#undef ISSUE
}

extern "C" void kernel_launch(void* const* d_in, const int* in_sizes, int n_in,
                              void* d_out, int out_size, void* d_ws, size_t ws_size,
                              hipStream_t stream)
{
    const float*    x      = (const float*)d_in[0];
    const uint32_t* stored = (const uint32_t*)d_in[1];
    const uint32_t* sign   = (const uint32_t*)d_in[2];
    const float*    lmin   = (const float*)d_in[3];
    const float*    lmax   = (const float*)d_in[4];
    const float*    bias   = (const float*)d_in[5];
    float* out = (float*)d_out;

    dim3 grid(OUT_F / RPB), block(WAVES * 64);
    qins_linear_kernel<<<grid, block, 0, stream>>>(x, stored, sign, lmin, lmax, bias, out);
}